// Round 5
// baseline (127.237 us; speedup 1.0000x reference)
//
#include <hip/hip_runtime.h>
#include <hip/hip_bf16.h>
#include <math.h>

// Problem constants (match reference setup_inputs)
#define NN 4096
#define MM 128
#define QQ 64
#define DD 128
#define CC (MM * QQ)          // 8192 gemm "columns" (flattened m,q)

typedef short bf16x8 __attribute__((ext_vector_type(8)));  // 8 bf16 = 4 VGPRs
typedef float f32x4  __attribute__((ext_vector_type(4)));

static __device__ inline unsigned short f2bf(float f) {
    __hip_bfloat16 h = __float2bfloat16(f);
    return *reinterpret_cast<unsigned short*>(&h);
}

// ---- pre-kernel: fp32->bf16 convert + exact fp32 squared norms ----
__global__ __launch_bounds__(256)
void prep_kernel(const float* __restrict__ A, const float* __restrict__ B,
                 unsigned short* __restrict__ Abf, unsigned short* __restrict__ Bbf,
                 float* __restrict__ a2, float* __restrict__ b2)
{
    const int row  = blockIdx.x * 4 + (threadIdx.x >> 6);   // 0..12287
    const int lane = threadIdx.x & 63;
    const float* src;
    unsigned short* dst;
    float* nrm;
    if (row < NN) { src = A + (size_t)row * DD; dst = Abf + (size_t)row * DD; nrm = a2 + row; }
    else {
        int r = row - NN;
        src = B + (size_t)r * DD; dst = Bbf + (size_t)r * DD; nrm = b2 + r;
    }
    float2 v = ((const float2*)src)[lane];
    ushort2 u; u.x = f2bf(v.x); u.y = f2bf(v.y);
    ((ushort2*)dst)[lane] = u;
    float s = v.x * v.x + v.y * v.y;
    #pragma unroll
    for (int off = 32; off > 0; off >>= 1) s += __shfl_down(s, off);
    if (lane == 0) *nrm = s;
}

// ---- fused main: register-resident A, B streamed global->VGPR, no LDS data path ----
// 256 blocks x 1024 threads. Block owns 16 n-rows and ALL 8192 c (so normalize
// fuses in-block). Wave w owns c in [w*512, w*512+512) = m in [w*8, w*8+8).
// Per m: 4 chunks of 16 cols; per chunk: 4 global b128 B-frag loads + 4 chained
// MFMAs (K=128) + exp epilogue. 2-chunk-pair software pipeline.
__global__ __launch_bounds__(1024, 4)
void kde_fused_kernel(const unsigned short* __restrict__ Abf,  // [NN][DD] bf16
                      const unsigned short* __restrict__ Bbf,  // [CC][DD] bf16
                      const float* __restrict__ var,
                      const float* __restrict__ a2w,           // [NN]
                      const float* __restrict__ b2w,           // [CC]
                      float* __restrict__ out)                 // [NN][MM]
{
    __shared__ float tab[16][132];     // dens[row][m], padded stride
    __shared__ float denom[16];

    const int t    = threadIdx.x;
    const int w    = t >> 6;           // 0..15
    const int lane = t & 63;
    const int l15  = lane & 15;
    const int q    = lane >> 4;
    const int n0   = blockIdx.x * 16;
    const int cw0  = w * 512;          // wave's col base
    const int mstart = blockIdx.x & 7; // rotate m order to spread L2 hotspot

    // persistent A fragments: lane holds A[n0+l15][ks*32 + q*8 .. +7]
    bf16x8 af[4];
    const unsigned short* Arow = Abf + (size_t)(n0 + l15) * DD;
    #pragma unroll
    for (int ks = 0; ks < 4; ++ks)
        af[ks] = *(const bf16x8*)&Arow[ks * 32 + q * 8];

    float a2v[4];
    #pragma unroll
    for (int r = 0; r < 4; ++r) a2v[r] = a2w[n0 + q * 4 + r];

    const float hinv = 0.5f / var[0];

    // pipeline state: ring of 2 chunk-pairs (each pair = 2 chunks x 4 ks b128)
    bf16x8 bb[2][2][4];
    float  b2r[2][2];

    // chunk index (0..31) for pipeline position p (0..15), chunk-in-pair cip
    #define CHUNK_OF(p, cip) ((((mstart + ((p) >> 1)) & 7) << 2) + (((p) & 1) << 1) + (cip))

    #define LOADPAIR(p, ring)                                                   \
        {                                                                       \
            _Pragma("unroll")                                                   \
            for (int cip = 0; cip < 2; ++cip) {                                 \
                const int cb = cw0 + CHUNK_OF(p, cip) * 16;                     \
                const unsigned short* Brow = Bbf + (size_t)(cb + l15) * DD;     \
                _Pragma("unroll")                                               \
                for (int ks = 0; ks < 4; ++ks)                                  \
                    bb[ring][cip][ks] = *(const bf16x8*)&Brow[ks * 32 + q * 8]; \
                b2r[ring][cip] = b2w[cb + l15];                                 \
            }                                                                   \
        }

    float dens_part[4] = {0.f, 0.f, 0.f, 0.f};

    #define COMPUTEPAIR(p, ring)                                                \
        {                                                                       \
            _Pragma("unroll")                                                   \
            for (int cip = 0; cip < 2; ++cip) {                                 \
                f32x4 acc = {0.f, 0.f, 0.f, 0.f};                               \
                _Pragma("unroll")                                               \
                for (int ks = 0; ks < 4; ++ks)                                  \
                    acc = __builtin_amdgcn_mfma_f32_16x16x32_bf16(              \
                              af[ks], bb[ring][cip][ks], acc, 0, 0, 0);         \
                const float b2c = b2r[ring][cip];                               \
                _Pragma("unroll")                                               \
                for (int r = 0; r < 4; ++r)                                     \
                    dens_part[r] += __expf((2.f * acc[r] - a2v[r] - b2c) * hinv); \
            }                                                                   \
            if (((p) & 1) == 1) {  /* end of this m: reduce over 16 cols-lanes */ \
                _Pragma("unroll")                                               \
                for (int mask = 1; mask < 16; mask <<= 1)                       \
                    _Pragma("unroll")                                           \
                    for (int r = 0; r < 4; ++r)                                 \
                        dens_part[r] += __shfl_xor(dens_part[r], mask, 64);     \
                if (l15 == 0) {                                                 \
                    const int m = (w << 3) + ((mstart + ((p) >> 1)) & 7);       \
                    _Pragma("unroll")                                           \
                    for (int r = 0; r < 4; ++r)                                 \
                        tab[q * 4 + r][m] = dens_part[r];                       \
                }                                                               \
                _Pragma("unroll")                                               \
                for (int r = 0; r < 4; ++r) dens_part[r] = 0.f;                 \
            }                                                                   \
        }

    LOADPAIR(0, 0);
    for (int p = 0; p < 16; p += 2) {
        if (p + 1 < 16) LOADPAIR(p + 1, 1);
        COMPUTEPAIR(p, 0);
        if (p + 2 < 16) LOADPAIR(p + 2, 0);
        COMPUTEPAIR(p + 1, 1);
    }
    __syncthreads();

    // row denominators: 256 threads, 16 per row
    if (t < 256) {
        const int row = t >> 4;
        const int j   = t & 15;
        const f32x4 s0 = *(const f32x4*)&tab[row][j * 8];
        const f32x4 s1 = *(const f32x4*)&tab[row][j * 8 + 4];
        f32x4 ss = s0 + s1;
        float s = ss[0] + ss[1] + ss[2] + ss[3];
        #pragma unroll
        for (int mask = 1; mask < 16; mask <<= 1)
            s += __shfl_xor(s, mask, 64);
        if (j == 0) denom[row] = s + 1e-10f;
    }
    __syncthreads();

    // normalized write-out: 2048 floats, coalesced float2 per thread
    {
        const int idx = t * 2;
        const int row = idx >> 7;
        const int m   = idx & 127;
        const float d = denom[row];
        float2 v;
        v.x = tab[row][m]     / d;
        v.y = tab[row][m + 1] / d;
        *(float2*)&out[(size_t)(n0 + row) * MM + m] = v;
    }
}

extern "C" void kernel_launch(void* const* d_in, const int* in_sizes, int n_in,
                              void* d_out, int out_size, void* d_ws, size_t ws_size,
                              hipStream_t stream) {
    const float* A   = (const float*)d_in[0];   // [4096][128]
    const float* B   = (const float*)d_in[1];   // [128][64][128] = [8192][128]
    const float* var = (const float*)d_in[2];   // [1]
    float* out = (float*)d_out;                 // [4096][128]

    unsigned short* Abf = (unsigned short*)d_ws;        // 1 MB
    unsigned short* Bbf = Abf + (size_t)NN * DD;        // 2 MB
    float* a2 = (float*)(Bbf + (size_t)CC * DD);        // 16 KB
    float* b2 = a2 + NN;                                // 32 KB

    prep_kernel<<<(NN + CC) / 4, 256, 0, stream>>>(A, B, Abf, Bbf, a2, b2);
    kde_fused_kernel<<<NN / 16, 1024, 0, stream>>>(Abf, Bbf, var, a2, b2, out);
}

// Round 6
// 85.904 us; speedup vs baseline: 1.4812x; 1.4812x over previous
//
#include <hip/hip_runtime.h>
#include <hip/hip_bf16.h>
#include <math.h>

// Problem constants (match reference setup_inputs)
#define NN 4096
#define MM 128
#define QQ 64
#define DD 128
#define CC (MM * QQ)          // 8192 gemm "columns" (flattened m,q)

typedef short bf16x8 __attribute__((ext_vector_type(8)));  // 8 bf16 = 4 VGPRs
typedef float f32x4  __attribute__((ext_vector_type(4)));

static __device__ inline unsigned short f2bf(float f) {
    __hip_bfloat16 h = __float2bfloat16(f);
    return *reinterpret_cast<unsigned short*>(&h);
}

// ---- prep: fp32->bf16 convert + exact fp32 squared norms, float4 loads ----
// Half-wave (32 lanes) per row: 32 x float4 = 512 B = one 128-float row.
__global__ __launch_bounds__(256)
void prep_kernel(const float* __restrict__ A, const float* __restrict__ B,
                 unsigned short* __restrict__ Abf, unsigned short* __restrict__ Bbf,
                 float* __restrict__ a2, float* __restrict__ b2)
{
    const int row = blockIdx.x * 8 + (threadIdx.x >> 5);    // 0..12287
    const int l32 = threadIdx.x & 31;
    const float* src;
    unsigned short* dst;
    float* nrm;
    if (row < NN) { src = A + (size_t)row * DD; dst = Abf + (size_t)row * DD; nrm = a2 + row; }
    else {
        int r = row - NN;
        src = B + (size_t)r * DD; dst = Bbf + (size_t)r * DD; nrm = b2 + r;
    }
    float4 v = ((const float4*)src)[l32];
    ushort4 u;
    u.x = f2bf(v.x); u.y = f2bf(v.y); u.z = f2bf(v.z); u.w = f2bf(v.w);
    ((ushort4*)dst)[l32] = u;
    float s = v.x * v.x + v.y * v.y + v.z * v.z + v.w * v.w;
    #pragma unroll
    for (int m = 16; m > 0; m >>= 1) s += __shfl_xor(s, m, 64);  // stays in 32-group
    if (l32 == 0) *nrm = s;
}

// ---- main: bf16 MFMA (one-shot K=128), 128 n-rows x 128 c-cols (= 2 m) per block ----
// LDS rows 0..127 = A tile, 128..255 = B tile. Pad-free (global_load_lds), XOR
// chunk swizzle (cb ^= row&7) for conflict-free ds_read_b128 frags.
// 64 KB LDS, 512 threads, 2 blocks/CU. dens written transposed: dpc[m][n].
__global__ __launch_bounds__(512, 4)
void kde_mfma_kernel(const unsigned short* __restrict__ Abf,  // [NN][DD] bf16
                     const unsigned short* __restrict__ Bbf,  // [CC][DD] bf16
                     const float* __restrict__ var,
                     const float* __restrict__ a2w,           // [NN]
                     const float* __restrict__ b2w,           // [CC]
                     float* __restrict__ dpc)                 // [MM][NN] transposed
{
    __shared__ unsigned short Tile[256 * DD];   // 64 KB
    __shared__ float a2s[128];
    __shared__ float b2s[128];
    __shared__ float red[8][32];                // per-wave store-coalescing buffer

    // XCD swizzle: XCD x owns cb in [8x, 8x+8) -> per-XCD B slab 256 KB + A 1 MB (L2-fit)
    const int lin = blockIdx.x;                 // 0..2047
    const int xcd = lin & 7;
    const int loc = lin >> 3;                   // 0..255
    const int cb  = (xcd << 3) | (loc & 7);     // 0..63
    const int nb  = loc >> 3;                   // 0..31
    const int n0  = nb * 128;
    const int c0  = cb * 128;

    const int t    = threadIdx.x;
    const int w    = t >> 6;                    // 0..7
    const int lane = t & 63;

    // ---- async staging: 4096 16B chunks (A 2048 + B 2048), 8 instrs/wave ----
    const unsigned short* Ab = Abf + (size_t)n0 * DD;
    const unsigned short* Bb = Bbf + (size_t)c0 * DD;
    #pragma unroll
    for (int i = 0; i < 8; ++i) {
        const int slot = w * 512 + i * 64 + lane;    // 0..4095
        const int r    = slot >> 4;                  // LDS row 0..255
        const int c16  = slot & 15;
        const int scb  = c16 ^ (r & 7);              // swizzled source chunk
        const unsigned short* g = (r < 128) ? (Ab + r * DD + scb * 8)
                                            : (Bb + (r - 128) * DD + scb * 8);
        unsigned short* lbase = &Tile[(w * 512 + i * 64) * 8];   // wave-uniform
        __builtin_amdgcn_global_load_lds(
            (const __attribute__((address_space(1))) unsigned int*)g,
            (__attribute__((address_space(3))) unsigned int*)lbase,
            16, 0, 0);
    }
    if (t < 128)            a2s[t]       = a2w[n0 + t];
    else if (t < 256)       b2s[t - 128] = b2w[c0 + (t - 128)];
    __syncthreads();   // drains vmcnt(0) incl. global_load_lds

    // ---- MFMA: wave w -> rows (w&3)*32, cols (w>>2)*64 (one m per wave) ----
    const int l15   = lane & 15;
    const int q     = lane >> 4;
    const int xr    = l15 & 7;
    const int rbase = (w & 3) * 32;
    const int cbase = (w >> 2) * 64;

    f32x4 acc[2][4] = {};
    #pragma unroll
    for (int ks = 0; ks < 4; ++ks) {            // K = 4 * 32
        const int off = ((ks * 4 + q) ^ xr) * 8;
        bf16x8 af[2], bf[4];
        #pragma unroll
        for (int i = 0; i < 2; ++i)
            af[i] = *(const bf16x8*)&Tile[(rbase + i * 16 + l15) * DD + off];
        #pragma unroll
        for (int j = 0; j < 4; ++j)
            bf[j] = *(const bf16x8*)&Tile[(128 + cbase + j * 16 + l15) * DD + off];
        #pragma unroll
        for (int i = 0; i < 2; ++i)
            #pragma unroll
            for (int j = 0; j < 4; ++j)
                acc[i][j] = __builtin_amdgcn_mfma_f32_16x16x32_bf16(
                                af[i], bf[j], acc[i][j], 0, 0, 0);
    }

    // ---- epilogue: exp + sum over the wave's 64 cols (= one m) ----
    const float hinv = 0.5f / var[0];
    float rowsum[2][4];
    #pragma unroll
    for (int i = 0; i < 2; ++i) {
        #pragma unroll
        for (int reg = 0; reg < 4; ++reg) {
            const float a2 = a2s[rbase + i * 16 + q * 4 + reg];
            float p = 0.f;
            #pragma unroll
            for (int j = 0; j < 4; ++j) {
                const float b2 = b2s[cbase + j * 16 + l15];
                p += __expf((2.f * acc[i][j][reg] - a2 - b2) * hinv);
            }
            rowsum[i][reg] = p;
        }
    }
    #pragma unroll
    for (int mask = 1; mask < 16; mask <<= 1)
        #pragma unroll
        for (int i = 0; i < 2; ++i)
            #pragma unroll
            for (int reg = 0; reg < 4; ++reg)
                rowsum[i][reg] += __shfl_xor(rowsum[i][reg], mask, 64);

    // coalesce via wave-private LDS: 4 lanes (l15==0) hold all 32 row sums
    if (l15 == 0) {
        #pragma unroll
        for (int i = 0; i < 2; ++i)
            #pragma unroll
            for (int reg = 0; reg < 4; ++reg)
                red[w][i * 16 + q * 4 + reg] = rowsum[i][reg];
    }
    // wave-private region: in-order LDS pipe + compiler lgkmcnt, no barrier needed
    const int m = (cb << 1) + (w >> 2);
    if (lane < 32)
        dpc[(size_t)m * NN + n0 + rbase + lane] = red[w][lane];
}

// ---- normalize: out[n,m] = dpc[m,n] / (sum_m dpc[:,n] + 1e-10), coalesced ----
__global__ __launch_bounds__(1024)
void kde_norm_kernel(const float* __restrict__ dpc, float* __restrict__ out)
{
    __shared__ float tile[MM][65];     // [m][nloc], odd stride
    __shared__ float rden[64];
    const int n0 = blockIdx.x * 64;
    const int t  = threadIdx.x;

    // stage 128 m x 64 n slab, coalesced float4 reads
    #pragma unroll
    for (int it = 0; it < 2; ++it) {
        const int m  = (t >> 4) + it * 64;
        const int nc = (t & 15) * 4;
        float4 v = *(const float4*)&dpc[(size_t)m * NN + n0 + nc];
        tile[m][nc]     = v.x;
        tile[m][nc + 1] = v.y;
        tile[m][nc + 2] = v.z;
        tile[m][nc + 3] = v.w;
    }
    __syncthreads();

    if (t < 64) {
        float s = 0.f;
        #pragma unroll 8
        for (int m = 0; m < MM; ++m) s += tile[m][t];
        rden[t] = 1.f / (s + 1e-10f);
    }
    __syncthreads();

    // write out[n][m], coalesced: thread covers 8 consecutive m of one n-row
    const int nloc = t >> 4;
    const int m0   = (t & 15) * 8;
    const float r  = rden[nloc];
    float4 o0, o1;
    o0.x = tile[m0][nloc] * r;     o0.y = tile[m0 + 1][nloc] * r;
    o0.z = tile[m0 + 2][nloc] * r; o0.w = tile[m0 + 3][nloc] * r;
    o1.x = tile[m0 + 4][nloc] * r; o1.y = tile[m0 + 5][nloc] * r;
    o1.z = tile[m0 + 6][nloc] * r; o1.w = tile[m0 + 7][nloc] * r;
    float* obase = &out[(size_t)(n0 + nloc) * MM + m0];
    *(float4*)obase       = o0;
    *(float4*)(obase + 4) = o1;
}

extern "C" void kernel_launch(void* const* d_in, const int* in_sizes, int n_in,
                              void* d_out, int out_size, void* d_ws, size_t ws_size,
                              hipStream_t stream) {
    const float* A   = (const float*)d_in[0];   // [4096][128]
    const float* B   = (const float*)d_in[1];   // [128][64][128] = [8192][128]
    const float* var = (const float*)d_in[2];   // [1]
    float* out = (float*)d_out;                 // [4096][128]

    unsigned short* Abf = (unsigned short*)d_ws;        // 1 MB
    unsigned short* Bbf = Abf + (size_t)NN * DD;        // 2 MB
    float* a2  = (float*)(Bbf + (size_t)CC * DD);       // 16 KB
    float* b2  = a2 + NN;                               // 32 KB
    float* dpc = b2 + CC;                               // 2 MB, [MM][NN]

    prep_kernel<<<(NN + CC) / 8, 256, 0, stream>>>(A, B, Abf, Bbf, a2, b2);
    kde_mfma_kernel<<<2048, 512, 0, stream>>>(Abf, Bbf, var, a2, b2, dpc);
    kde_norm_kernel<<<NN / 64, 1024, 0, stream>>>(dpc, out);
}